// Round 2
// baseline (215.480 us; speedup 1.0000x reference)
//
#include <hip/hip_runtime.h>
#include <hip/hip_bf16.h>

#define NPTS   16384
#define NPAIRS 65536

// ws layout:
//   [0..32)   : double acc[4]  {partSum, kldRaw, S1, S2}
//   [256.. )  : float4 xt[NPTS]  {x0, x1, x2+1, 0}

__device__ inline float waveReduce(float v) {
#pragma unroll
    for (int o = 32; o > 0; o >>= 1) v += __shfl_down(v, o, 64);
    return v;
}

// ---------------- kernel A: fused reparam-table + per-pair loss ----------------
__global__ __launch_bounds__(256) void k_prep(
        const float2* __restrict__ mu, const float2* __restrict__ lv,
        const float2* __restrict__ ef, float4* __restrict__ xt,
        const float* __restrict__ pij, const int* __restrict__ ii,
        const int* __restrict__ jj,
        const float2* __restrict__ ei, const float2* __restrict__ ej,
        double* __restrict__ acc) {
    int b = blockIdx.x;
    if (b < NPTS / 256) {
        // ---- points: x = eps*exp(0.5*lv)+mu, store {x0,x1,x^2+1}, kld reduce
        int i = b * 256 + threadIdx.x;
        float2 m = mu[i], l = lv[i], e = ef[i];
        float x0 = fmaf(e.x, expf(0.5f * l.x), m.x);
        float x1 = fmaf(e.y, expf(0.5f * l.y), m.y);
        float w  = fmaf(x0, x0, x1 * x1) + 1.0f;
        xt[i] = make_float4(x0, x1, w, 0.0f);
        float k = (1.0f + l.x - m.x * m.x - expf(l.x))
                + (1.0f + l.y - m.y * m.y - expf(l.y));
        k = waveReduce(k);
        if ((threadIdx.x & 63) == 0) atomicAdd(&acc[1], (double)k);
    } else {
        // ---- pairs: pij*(log pij + log1p(|xi-xj|^2)), and sum(pij)
        int p = (b - NPTS / 256) * 256 + threadIdx.x;
        float pv = pij[p];
        int a = ii[p], bb = jj[p];
        float2 ma = mu[a], la = lv[a], ea = ei[p];
        float2 mb = mu[bb], lb = lv[bb], eb = ej[p];
        float xa0 = fmaf(ea.x, expf(0.5f * la.x), ma.x);
        float xa1 = fmaf(ea.y, expf(0.5f * la.y), ma.y);
        float xb0 = fmaf(eb.x, expf(0.5f * lb.x), mb.x);
        float xb1 = fmaf(eb.y, expf(0.5f * lb.y), mb.y);
        float d0 = xa0 - xb0, d1 = xa1 - xb1;
        float dsq = fmaf(d0, d0, d1 * d1);
        float t = pv * (logf(pv) + log1pf(dsq));
        float s1 = waveReduce(t);
        float s2 = waveReduce(pv);
        if ((threadIdx.x & 63) == 0) {
            atomicAdd(&acc[2], (double)s1);
            atomicAdd(&acc[3], (double)s2);
        }
    }
}

// ---------------- kernel B: N^2 normalizer (dominant) ----------------
// Each thread: 8 columns in registers {2x0, 2x1, x^2}; rows broadcast via
// wave-uniform scalar loads. No LDS, no barriers. 8 independent acc chains.
// Grid (8, 256): 8 col-groups x 2048 cols, 256 row-groups x 64 rows.
__global__ __launch_bounds__(256) void k_part(
        const float4* __restrict__ xt, double* __restrict__ acc) {
    int colBase = blockIdx.x * 2048;
    int rowBase = blockIdx.y * 64;

    float c0[8], c1[8], cw[8], a[8];
#pragma unroll
    for (int k = 0; k < 8; ++k) {
        float4 c = xt[colBase + (int)threadIdx.x + k * 256];
        c0[k] = 2.0f * c.x;        // 2*x0_j
        c1[k] = 2.0f * c.y;        // 2*x1_j
        cw[k] = c.z - 1.0f;        // x_j^2
        a[k]  = 0.0f;
    }

#pragma unroll 4
    for (int r = 0; r < 64; ++r) {
        float4 rv = xt[rowBase + r];   // wave-uniform -> s_load_dwordx4
        float rw = rv.z;               // x_i^2 + 1
#pragma unroll
        for (int k = 0; k < 8; ++k) {
            float e = rw + cw[k];                 // 1 + xi^2 + xj^2
            e = fmaf(-rv.x, c0[k], e);            // - 2*x0i*x0j
            e = fmaf(-rv.y, c1[k], e);            // - 2*x1i*x1j
            e = fmaxf(e, 1.0f);
            a[k] += __builtin_amdgcn_rcpf(e);
        }
    }
    float s = ((a[0] + a[1]) + (a[2] + a[3])) + ((a[4] + a[5]) + (a[6] + a[7]));
    s = waveReduce(s);
    if ((threadIdx.x & 63) == 0) atomicAdd(&acc[0], (double)s);
}

// ---------------- kernel C: finalize ----------------
__global__ void k_final(const double* __restrict__ acc, float* __restrict__ out) {
    double part = acc[0] - (double)NPTS;
    double res = acc[2] + acc[3] * log(part) - 0.5e-7 * acc[1];
    out[0] = (float)res;
}

extern "C" void kernel_launch(void* const* d_in, const int* in_sizes, int n_in,
                              void* d_out, int out_size, void* d_ws, size_t ws_size,
                              hipStream_t stream) {
    const float*  pij = (const float*)d_in[0];
    const int*    ii  = (const int*)d_in[1];
    const int*    jj  = (const int*)d_in[2];
    const float2* mu  = (const float2*)d_in[3];
    const float2* lv  = (const float2*)d_in[4];
    const float2* ef  = (const float2*)d_in[5];
    const float2* ei  = (const float2*)d_in[6];
    const float2* ej  = (const float2*)d_in[7];
    float* out  = (float*)d_out;
    double* acc = (double*)d_ws;
    float4* xt  = (float4*)((char*)d_ws + 256);

    hipMemsetAsync(d_ws, 0, 256, stream);
    k_prep<<<NPTS / 256 + NPAIRS / 256, 256, 0, stream>>>(mu, lv, ef, xt,
                                                          pij, ii, jj, ei, ej, acc);
    dim3 gb(8, 256);
    k_part<<<gb, 256, 0, stream>>>(xt, acc);
    k_final<<<1, 1, 0, stream>>>(acc, out);
}

// Round 3
// 125.676 us; speedup vs baseline: 1.7146x; 1.7146x over previous
//
#include <hip/hip_runtime.h>

#define NPTS   16384
#define NPAIRS 65536

// ws layout (bytes):
//   [0,      131072)  float2 xt[16384]          {x0, x1}
//   [131072, 147456)  double partPart[2048]     k_part block partials (upper-tri sum)
//   [147456, 149504)  double kldPart[256]       k_prep point-block partials
//   [149504, 157696)  double s1Part[1024]       k_prep pair-block partials: pij*(log pij + log1p(d^2))
//   [157696, 165888)  double s2Part[1024]       k_prep pair-block partials: pij

__device__ inline float waveReduceF(float v) {
#pragma unroll
    for (int o = 32; o > 0; o >>= 1) v += __shfl_down(v, o, 64);
    return v;
}

// ---------------- kernel A: reparam table + per-pair loss (1 wave/block) ----------------
__global__ __launch_bounds__(64) void k_prep(
        const float2* __restrict__ mu, const float2* __restrict__ lv,
        const float2* __restrict__ ef,
        const float* __restrict__ pij, const int* __restrict__ ii,
        const int* __restrict__ jj,
        const float2* __restrict__ ei, const float2* __restrict__ ej,
        float2* __restrict__ xt,
        double* __restrict__ kldPart, double* __restrict__ s1Part,
        double* __restrict__ s2Part) {
    int b = blockIdx.x;
    int lane = threadIdx.x;
    if (b < NPTS / 64) {
        int i = b * 64 + lane;
        float2 m = mu[i], l = lv[i], e = ef[i];
        float x0 = fmaf(e.x, expf(0.5f * l.x), m.x);
        float x1 = fmaf(e.y, expf(0.5f * l.y), m.y);
        xt[i] = make_float2(x0, x1);
        float k = (1.0f + l.x - m.x * m.x - expf(l.x))
                + (1.0f + l.y - m.y * m.y - expf(l.y));
        k = waveReduceF(k);
        if (lane == 0) kldPart[b] = (double)k;
    } else {
        int p = (b - NPTS / 64) * 64 + lane;
        float pv = pij[p];
        int a = ii[p], bb = jj[p];
        float2 ma = mu[a], la = lv[a], ea = ei[p];
        float2 mb = mu[bb], lb = lv[bb], eb = ej[p];
        float xa0 = fmaf(ea.x, expf(0.5f * la.x), ma.x);
        float xa1 = fmaf(ea.y, expf(0.5f * la.y), ma.y);
        float xb0 = fmaf(eb.x, expf(0.5f * lb.x), mb.x);
        float xb1 = fmaf(eb.y, expf(0.5f * lb.y), mb.y);
        float d0 = xa0 - xb0, d1 = xa1 - xb1;
        float dsq = fmaf(d0, d0, d1 * d1);
        float t = pv * (logf(pv) + log1pf(dsq));
        float s1 = waveReduceF(t);
        float s2 = waveReduceF(pv);
        if (lane == 0) {
            s1Part[b - NPTS / 64] = (double)s1;
            s2Part[b - NPTS / 64] = (double)s2;
        }
    }
}

// ---------------- kernel B: N^2 normalizer, upper triangle only ----------------
// part = 2 * sum_{j>i} 1/(1 + |xi-xj|^2).  Each thread owns 8 columns in
// registers; rows broadcast from registers via v_readlane (no memory, no LDS
// in the loop).  Grid (8, 256): cols in 8 groups of 2048, rows in 256 groups
// of 64.  Tiles fully below the diagonal exit early (still write their 0).
__global__ __launch_bounds__(256) void k_part(
        const float2* __restrict__ xt, double* __restrict__ partPart) {
    int bx = blockIdx.x, by = blockIdx.y;
    int colBase = bx * 2048, rowBase = by * 64;
    double* slot = &partPart[by * 8 + bx];

    if (colBase + 2048 <= rowBase) {            // whole tile j < i: dead
        if (threadIdx.x == 0) *slot = 0.0;
        return;
    }
    int tid = threadIdx.x;
    float cx[8], cy[8], a[8];
    int jcol[8];
#pragma unroll
    for (int k = 0; k < 8; ++k) {
        int j = colBase + tid + k * 256;
        float2 c = xt[j];
        cx[k] = c.x; cy[k] = c.y; a[k] = 0.0f; jcol[k] = j;
    }
    float2 rv = xt[rowBase + (tid & 63)];

    if (colBase >= rowBase + 64) {              // whole tile j > i: no mask
#pragma unroll 8
        for (int r = 0; r < 64; ++r) {
            float rx = __int_as_float(__builtin_amdgcn_readlane(__float_as_int(rv.x), r));
            float ry = __int_as_float(__builtin_amdgcn_readlane(__float_as_int(rv.y), r));
#pragma unroll
            for (int k = 0; k < 8; ++k) {
                float d0 = rx - cx[k], d1 = ry - cy[k];
                float e = fmaf(d1, d1, fmaf(d0, d0, 1.0f));
                a[k] += __builtin_amdgcn_rcpf(e);
            }
        }
    } else {                                    // diagonal band: mask j > i
#pragma unroll 8
        for (int r = 0; r < 64; ++r) {
            int irow = rowBase + r;
            float rx = __int_as_float(__builtin_amdgcn_readlane(__float_as_int(rv.x), r));
            float ry = __int_as_float(__builtin_amdgcn_readlane(__float_as_int(rv.y), r));
#pragma unroll
            for (int k = 0; k < 8; ++k) {
                float d0 = rx - cx[k], d1 = ry - cy[k];
                float e = fmaf(d1, d1, fmaf(d0, d0, 1.0f));
                float v = __builtin_amdgcn_rcpf(e);
                a[k] += (jcol[k] > irow) ? v : 0.0f;
            }
        }
    }
    float s = ((a[0] + a[1]) + (a[2] + a[3])) + ((a[4] + a[5]) + (a[6] + a[7]));
    s = waveReduceF(s);
    __shared__ float ws4[4];
    if ((tid & 63) == 0) ws4[tid >> 6] = s;
    __syncthreads();
    if (tid == 0)
        *slot = ((double)ws4[0] + (double)ws4[1]) + ((double)ws4[2] + (double)ws4[3]);
}

// ---------------- kernel C: final reduce (1 wave) ----------------
__global__ __launch_bounds__(64) void k_final(
        const double* __restrict__ partPart, const double* __restrict__ kldPart,
        const double* __restrict__ s1Part, const double* __restrict__ s2Part,
        float* __restrict__ out) {
    int lane = threadIdx.x;
    double ps = 0.0, kld = 0.0, s1 = 0.0, s2 = 0.0;
#pragma unroll
    for (int k = 0; k < 32; ++k) ps += partPart[lane + k * 64];
#pragma unroll
    for (int k = 0; k < 4; ++k) kld += kldPart[lane + k * 64];
#pragma unroll
    for (int k = 0; k < 16; ++k) { s1 += s1Part[lane + k * 64]; s2 += s2Part[lane + k * 64]; }
#pragma unroll
    for (int o = 32; o > 0; o >>= 1) {
        ps  += __shfl_down(ps, o, 64);
        kld += __shfl_down(kld, o, 64);
        s1  += __shfl_down(s1, o, 64);
        s2  += __shfl_down(s2, o, 64);
    }
    if (lane == 0) {
        double part = 2.0 * ps;                 // diagonal cancels: sum_all - N = 2*S_upper
        out[0] = (float)(s1 + s2 * log(part) - 0.5e-7 * kld);
    }
}

extern "C" void kernel_launch(void* const* d_in, const int* in_sizes, int n_in,
                              void* d_out, int out_size, void* d_ws, size_t ws_size,
                              hipStream_t stream) {
    const float*  pij = (const float*)d_in[0];
    const int*    ii  = (const int*)d_in[1];
    const int*    jj  = (const int*)d_in[2];
    const float2* mu  = (const float2*)d_in[3];
    const float2* lv  = (const float2*)d_in[4];
    const float2* ef  = (const float2*)d_in[5];
    const float2* ei  = (const float2*)d_in[6];
    const float2* ej  = (const float2*)d_in[7];
    float* out = (float*)d_out;

    char* ws = (char*)d_ws;
    float2* xt      = (float2*)ws;
    double* partPart = (double*)(ws + 131072);
    double* kldPart  = (double*)(ws + 147456);
    double* s1Part   = (double*)(ws + 149504);
    double* s2Part   = (double*)(ws + 157696);

    k_prep<<<NPTS / 64 + NPAIRS / 64, 64, 0, stream>>>(mu, lv, ef, pij, ii, jj,
                                                       ei, ej, xt, kldPart, s1Part, s2Part);
    dim3 gb(8, 256);
    k_part<<<gb, 256, 0, stream>>>(xt, partPart);
    k_final<<<1, 64, 0, stream>>>(partPart, kldPart, s1Part, s2Part, out);
}

// Round 5
// 105.412 us; speedup vs baseline: 2.0442x; 1.1922x over previous
//
#include <hip/hip_runtime.h>

#define NPTS   16384
#define NPAIRS 65536

// ws layout (bytes):
//   [0,      131072)  float2 xt[16384]        {x0, x1}
//   [131072, 147456)  double partPart[2048]   k_part per-block partials (upper-tri sum)
//   [147456, 149504)  double kldPart[256]     k_prep per-wave point partials
//   [149504, 157696)  double s1Part[1024]     k_prep per-wave pair partials: pij*(log pij + log1p(d^2))
//   [157696, 165888)  double s2Part[1024]     k_prep per-wave pair partials: pij

__device__ inline float waveReduceF(float v) {
#pragma unroll
    for (int o = 32; o > 0; o >>= 1) v += __shfl_down(v, o, 64);
    return v;
}

// ---------------- kernel A: reparam table + per-pair loss ----------------
__global__ __launch_bounds__(256) void k_prep(
        const float2* __restrict__ mu, const float2* __restrict__ lv,
        const float2* __restrict__ ef,
        const float* __restrict__ pij, const int* __restrict__ ii,
        const int* __restrict__ jj,
        const float2* __restrict__ ei, const float2* __restrict__ ej,
        float2* __restrict__ xt,
        double* __restrict__ kldPart, double* __restrict__ s1Part,
        double* __restrict__ s2Part) {
    int b = blockIdx.x;
    int tid = threadIdx.x;
    int wave = tid >> 6;
    if (b < NPTS / 256) {
        int i = b * 256 + tid;
        float2 m = mu[i], l = lv[i], e = ef[i];
        float x0 = fmaf(e.x, expf(0.5f * l.x), m.x);
        float x1 = fmaf(e.y, expf(0.5f * l.y), m.y);
        xt[i] = make_float2(x0, x1);
        float k = (1.0f + l.x - m.x * m.x - expf(l.x))
                + (1.0f + l.y - m.y * m.y - expf(l.y));
        k = waveReduceF(k);
        if ((tid & 63) == 0) kldPart[b * 4 + wave] = (double)k;
    } else {
        int pb = b - NPTS / 256;
        int p = pb * 256 + tid;
        float pv = pij[p];
        int a = ii[p], bb = jj[p];
        float2 ma = mu[a], la = lv[a], ea = ei[p];
        float2 mb = mu[bb], lb = lv[bb], eb = ej[p];
        float xa0 = fmaf(ea.x, expf(0.5f * la.x), ma.x);
        float xa1 = fmaf(ea.y, expf(0.5f * la.y), ma.y);
        float xb0 = fmaf(eb.x, expf(0.5f * lb.x), mb.x);
        float xb1 = fmaf(eb.y, expf(0.5f * lb.y), mb.y);
        float d0 = xa0 - xb0, d1 = xa1 - xb1;
        float dsq = fmaf(d0, d0, d1 * d1);
        float t = pv * (logf(pv) + log1pf(dsq));
        float s1 = waveReduceF(t);
        float s2 = waveReduceF(pv);
        if ((tid & 63) == 0) {
            s1Part[pb * 4 + wave] = (double)s1;
            s2Part[pb * 4 + wave] = (double)s2;
        }
    }
}

// ---------------- kernel B: N^2 normalizer, balanced upper triangle ----------------
// part = 2 * sum_{j>i} 1/(1+|xi-xj|^2).  Block (bx,by): rows [64*by, 64*by+64),
// columns {j : j == bx (mod 8)} in 8 chunks of 2048 (thread tid owns column
// bx + 8*(tid + 256*k) of chunk k).  Chunk k: dead if k < kb, boundary-masked
// if k == kb, fully live if k > kb, where kb = by>>5.  Work per block is
// proportional to (8-kb); a CU's 8 blocks get kb = 0..7 exactly once ->
// every CU does 36 chunk-panels: perfectly balanced triangle.
template<int KB>
__device__ __forceinline__ float partBody(const float2* __restrict__ xt,
                                          int bx, int rowBase, int tid) {
    constexpr int NK = 8 - KB;
    float cx[NK], cy[NK], a[NK];
    int j0 = bx + 8 * (tid + 256 * KB);
#pragma unroll
    for (int m = 0; m < NK; ++m) {
        float2 c = xt[j0 + 2048 * m];
        cx[m] = c.x; cy[m] = c.y; a[m] = 0.0f;
    }
    float2 rv = xt[rowBase + (tid & 63)];
#pragma unroll 4
    for (int r = 0; r < 64; ++r) {
        float rx = __int_as_float(__builtin_amdgcn_readlane(__float_as_int(rv.x), r));
        float ry = __int_as_float(__builtin_amdgcn_readlane(__float_as_int(rv.y), r));
        {   // chunk KB: boundary, mask j > i
            float d0 = rx - cx[0], d1 = ry - cy[0];
            float e = fmaf(d1, d1, fmaf(d0, d0, 1.0f));
            float v = __builtin_amdgcn_rcpf(e);
            a[0] += (j0 > rowBase + r) ? v : 0.0f;
        }
#pragma unroll
        for (int m = 1; m < NK; ++m) {   // chunks > KB: fully live
            float d0 = rx - cx[m], d1 = ry - cy[m];
            float e = fmaf(d1, d1, fmaf(d0, d0, 1.0f));
            a[m] += __builtin_amdgcn_rcpf(e);
        }
    }
    float s = 0.0f;
#pragma unroll
    for (int m = 0; m < NK; ++m) s += a[m];
    return s;
}

__global__ __launch_bounds__(256) void k_part(
        const float2* __restrict__ xt, double* __restrict__ partPart) {
    int bx = blockIdx.x, by = blockIdx.y;
    int rowBase = by * 64;
    int kb = by >> 5;
    int tid = threadIdx.x;
    float s = 0.0f;
    switch (kb) {               // wave-uniform branch
        case 0: s = partBody<0>(xt, bx, rowBase, tid); break;
        case 1: s = partBody<1>(xt, bx, rowBase, tid); break;
        case 2: s = partBody<2>(xt, bx, rowBase, tid); break;
        case 3: s = partBody<3>(xt, bx, rowBase, tid); break;
        case 4: s = partBody<4>(xt, bx, rowBase, tid); break;
        case 5: s = partBody<5>(xt, bx, rowBase, tid); break;
        case 6: s = partBody<6>(xt, bx, rowBase, tid); break;
        default: s = partBody<7>(xt, bx, rowBase, tid); break;
    }
    s = waveReduceF(s);
    __shared__ float ws4[4];
    if ((tid & 63) == 0) ws4[tid >> 6] = s;
    __syncthreads();
    if (tid == 0)
        partPart[by * 8 + bx] =
            ((double)ws4[0] + (double)ws4[1]) + ((double)ws4[2] + (double)ws4[3]);
}

// ---------------- kernel C: final reduce (1 wave) ----------------
__global__ __launch_bounds__(64) void k_final(
        const double* __restrict__ partPart, const double* __restrict__ kldPart,
        const double* __restrict__ s1Part, const double* __restrict__ s2Part,
        float* __restrict__ out) {
    int lane = threadIdx.x;
    double ps = 0.0, kld = 0.0, s1 = 0.0, s2 = 0.0;
#pragma unroll
    for (int k = 0; k < 32; ++k) ps += partPart[lane + k * 64];
#pragma unroll
    for (int k = 0; k < 4; ++k) kld += kldPart[lane + k * 64];
#pragma unroll
    for (int k = 0; k < 16; ++k) { s1 += s1Part[lane + k * 64]; s2 += s2Part[lane + k * 64]; }
#pragma unroll
    for (int o = 32; o > 0; o >>= 1) {
        ps  += __shfl_down(ps, o, 64);
        kld += __shfl_down(kld, o, 64);
        s1  += __shfl_down(s1, o, 64);
        s2  += __shfl_down(s2, o, 64);
    }
    if (lane == 0) {
        double part = 2.0 * ps;      // diagonal cancels: sum_all - N = 2*S_upper
        out[0] = (float)(s1 + s2 * log(part) - 0.5e-7 * kld);
    }
}

extern "C" void kernel_launch(void* const* d_in, const int* in_sizes, int n_in,
                              void* d_out, int out_size, void* d_ws, size_t ws_size,
                              hipStream_t stream) {
    const float*  pij = (const float*)d_in[0];
    const int*    ii  = (const int*)d_in[1];
    const int*    jj  = (const int*)d_in[2];
    const float2* mu  = (const float2*)d_in[3];
    const float2* lv  = (const float2*)d_in[4];
    const float2* ef  = (const float2*)d_in[5];
    const float2* ei  = (const float2*)d_in[6];
    const float2* ej  = (const float2*)d_in[7];
    float* out = (float*)d_out;

    char* ws = (char*)d_ws;
    float2* xt       = (float2*)ws;
    double* partPart = (double*)(ws + 131072);
    double* kldPart  = (double*)(ws + 147456);
    double* s1Part   = (double*)(ws + 149504);
    double* s2Part   = (double*)(ws + 157696);

    k_prep<<<NPTS / 256 + NPAIRS / 256, 256, 0, stream>>>(mu, lv, ef, pij, ii, jj,
                                                          ei, ej, xt, kldPart, s1Part, s2Part);
    dim3 gb(8, 256);
    k_part<<<gb, 256, 0, stream>>>(xt, partPart);
    k_final<<<1, 64, 0, stream>>>(partPart, kldPart, s1Part, s2Part, out);
}